// Round 1
// baseline (21.024 us; speedup 1.0000x reference)
//
#include <hip/hip_runtime.h>

#define MAXM 512

#if __has_builtin(__builtin_amdgcn_exp2f)
#define EXP2F(x) __builtin_amdgcn_exp2f(x)
#else
#define EXP2F(x) exp2f(x)
#endif

constexpr float LOG2E = 1.4426950408889634f;

// Each block: 512 threads handle 256 points. Thread tid = half*256 + lane.
// half 0 sums Gaussians [0, M/2), half 1 sums [M/2, M); combined via LDS.
__global__ __launch_bounds__(512)
void decoder_kernel(const float* __restrict__ origins,
                    const float* __restrict__ directions,
                    const float* __restrict__ latents,
                    float* __restrict__ out,
                    int N, int M)
{
    __shared__ float4 gmean[MAXM];   // mx, my, mdx, mdy
    __shared__ float2 gcoef[MAXM];   // -0.5*log2e/sx, -0.5*log2e/sy
    __shared__ float  psum[512];

    // Stage + preprocess Gaussian params into LDS (once per block).
    for (int j = threadIdx.x; j < M; j += blockDim.x) {
        const float* L = latents + j * 6;
        float mx  = L[0];
        float my  = L[1];
        float mdx = L[2];
        float mdy = L[3];
        float sx  = fmaxf(L[4], 0.0f) + 0.01f;   // relu + eps
        float sy  = fmaxf(L[5], 0.0f) + 0.01f;
        gmean[j] = make_float4(mx, my, mdx, mdy);
        gcoef[j] = make_float2(-0.5f * LOG2E / sx, -0.5f * LOG2E / sy);
    }
    __syncthreads();

    const int tid  = threadIdx.x;
    const int half = tid >> 8;       // 0 or 1
    const int lane = tid & 255;
    const int i    = blockIdx.x * 256 + lane;
    const int ii   = (i < N) ? i : (N > 0 ? N - 1 : 0);  // clamp for safe loads

    const float2 o = ((const float2*)origins)[ii];
    const float2 d = ((const float2*)directions)[ii];
    const float cdir = -500.0f * LOG2E;   // -0.5/0.001 * log2(e)

    const int Mh   = (M + 1) >> 1;
    const int jbeg = half * Mh;
    const int jend = (jbeg + Mh < M) ? (jbeg + Mh) : M;

    float s0 = 0.0f, s1 = 0.0f, s2 = 0.0f, s3 = 0.0f;

    auto term = [&](int j) -> float {
        float4 gm = gmean[j];
        float2 gc = gcoef[j];
        float tx  = o.x - gm.x;
        float ty  = o.y - gm.y;
        float tdx = d.x - gm.z;
        float tdy = d.y - gm.w;
        float e  = gc.x * (tx * tx);
        e = fmaf(gc.y * ty, ty, e);
        float d2 = fmaf(tdy, tdy, tdx * tdx);
        e = fmaf(cdir, d2, e);
        return EXP2F(e);
    };

    int j = jbeg;
    for (; j + 4 <= jend; j += 4) {
        s0 += term(j + 0);
        s1 += term(j + 1);
        s2 += term(j + 2);
        s3 += term(j + 3);
    }
    for (; j < jend; ++j) s0 += term(j);

    psum[tid] = (s0 + s1) + (s2 + s3);
    __syncthreads();

    if (tid < 256 && i < N) {
        float tot = psum[tid] + psum[tid + 256];
        out[i] = fminf(fmaxf(tot, 0.0f), 1.0f);
    }
}

extern "C" void kernel_launch(void* const* d_in, const int* in_sizes, int n_in,
                              void* d_out, int out_size, void* d_ws, size_t ws_size,
                              hipStream_t stream) {
    const float* origins    = (const float*)d_in[0];
    const float* directions = (const float*)d_in[1];
    const float* latents    = (const float*)d_in[2];
    float* out = (float*)d_out;

    int N = in_sizes[0] / 2;
    int M = in_sizes[2] / 6;
    if (M > MAXM) M = MAXM;   // problem spec: M = 512

    int nblocks = (N + 255) / 256;
    decoder_kernel<<<nblocks, 512, 0, stream>>>(origins, directions, latents, out, N, M);
}